// Round 9
// baseline (1165.443 us; speedup 1.0000x reference)
//
#include <hip/hip_runtime.h>
#include <math.h>

#define DIM 4096
#define T_CACHE 32768
#define T_TOTAL 32769  // cache + the just-appended token

// Workspace layout (float offsets). d_ws is re-poisoned 0xAA before every
// timed launch, so every word we read must be written first within this call.
#define Q_OFF     0                 // q vector (4096)
#define K_OFF     4096              // k vector (4096)
#define V_OFF     8192              // v vector (4096)
#define S_OFF     16384             // raw scaled scores, T_TOTAL floats
#define MAXP_OFF  49408             // per-scores-block max partials (1025)
#define STAT_OFF  50688             // [0] = global max M
#define DENP_OFF  50944             // per-chunk denominator partials (<=512)
#define PART_OFF  51712             // PV partials, n_chunks * DIM floats

// ---------------------------------------------------------------------------
// Kernel 1: q/k/v = x @ W.T + b.  One wave per output row; 3*4096 rows total.
// Row read is fully coalesced float4 (64 lanes * 16B = 1KB per step).
// ---------------------------------------------------------------------------
__global__ __launch_bounds__(256) void qkv_gemv(
    const float* __restrict__ x,
    const float* __restrict__ Wq, const float* __restrict__ bq,
    const float* __restrict__ Wk, const float* __restrict__ bk,
    const float* __restrict__ Wv, const float* __restrict__ bv,
    float* __restrict__ ws) {
  const int wave = threadIdx.x >> 6;
  const int lane = threadIdx.x & 63;
  const int g = blockIdx.x * 4 + wave;        // 0 .. 12287
  const int m = g >> 12;                      // 0=q, 1=k, 2=v
  const int r = g & 4095;

  const float* W = (m == 0) ? Wq : (m == 1) ? Wk : Wv;
  const float* b = (m == 0) ? bq : (m == 1) ? bk : bv;
  float* out = ws + (Q_OFF + m * 4096);

  const float4* row = (const float4*)(W + (size_t)r * DIM);
  const float4* xv  = (const float4*)x;

  float acc = 0.f;
#pragma unroll
  for (int j = 0; j < 16; ++j) {
    float4 a = row[lane + j * 64];
    float4 c = xv[lane + j * 64];
    acc += a.x * c.x + a.y * c.y + a.z * c.z + a.w * c.w;
  }
#pragma unroll
  for (int off = 32; off; off >>= 1) acc += __shfl_xor(acc, off);
  if (lane == 0) out[r] = acc + b[r];
}

// ---------------------------------------------------------------------------
// Kernel 2: scores[t] = dot(q, K[t]) * 1/64, plus per-block max partial.
// One wave handles 8 rows as two groups of 4 (4 independent accumulators ->
// 64 outstanding float4 loads per wave for HBM latency hiding). q fragment
// lives in 64 VGPRs.
// ---------------------------------------------------------------------------
__global__ __launch_bounds__(256) void scores_kernel(
    const float* __restrict__ Kc, float* __restrict__ ws) {
  const int wave = threadIdx.x >> 6;
  const int lane = threadIdx.x & 63;
  const int base = (blockIdx.x * 4 + wave) * 8;

  const float4* qv = (const float4*)(ws + Q_OFF);
  const float*  kvec = ws + K_OFF;
  float* s = ws + S_OFF;
  __shared__ float red[4];

  float4 qf[16];
#pragma unroll
  for (int j = 0; j < 16; ++j) qf[j] = qv[lane + j * 64];

  float wmax = -1e30f;

#pragma unroll
  for (int g = 0; g < 8; g += 4) {
    const int t0 = base + g;
    if (t0 >= T_TOTAL) break;
    // t0 is always valid here; t0+1..t0+3 may be past the end only in the
    // very last wave -> clamp their row pointer to row 0 of the group and
    // discard results via the guards below.
    const float4* rp[4];
    rp[0] = (const float4*)((t0 < T_CACHE) ? (Kc + (size_t)t0 * DIM) : kvec);
#pragma unroll
    for (int r = 1; r < 4; ++r) {
      const int t = t0 + r;
      rp[r] = (t < T_TOTAL)
                  ? (const float4*)((t < T_CACHE) ? (Kc + (size_t)t * DIM)
                                                  : kvec)
                  : rp[0];
    }
    float a0 = 0.f, a1 = 0.f, a2 = 0.f, a3 = 0.f;
#pragma unroll
    for (int j = 0; j < 16; ++j) {
      const int idx = lane + j * 64;
      float4 k0 = rp[0][idx];
      float4 k1 = rp[1][idx];
      float4 k2 = rp[2][idx];
      float4 k3 = rp[3][idx];
      const float4 q = qf[j];
      a0 += k0.x * q.x + k0.y * q.y + k0.z * q.z + k0.w * q.w;
      a1 += k1.x * q.x + k1.y * q.y + k1.z * q.z + k1.w * q.w;
      a2 += k2.x * q.x + k2.y * q.y + k2.z * q.z + k2.w * q.w;
      a3 += k3.x * q.x + k3.y * q.y + k3.z * q.z + k3.w * q.w;
    }
#pragma unroll
    for (int off = 32; off; off >>= 1) {
      a0 += __shfl_xor(a0, off);
      a1 += __shfl_xor(a1, off);
      a2 += __shfl_xor(a2, off);
      a3 += __shfl_xor(a3, off);
    }
    a0 *= 0.015625f; a1 *= 0.015625f; a2 *= 0.015625f; a3 *= 0.015625f;
    // All lanes hold the reduced sums; guard per-row validity.
    wmax = fmaxf(wmax, a0);
    if (t0 + 1 < T_TOTAL) wmax = fmaxf(wmax, a1);
    if (t0 + 2 < T_TOTAL) wmax = fmaxf(wmax, a2);
    if (t0 + 3 < T_TOTAL) wmax = fmaxf(wmax, a3);
    if (lane == 0) {
      s[t0] = a0;
      if (t0 + 1 < T_TOTAL) s[t0 + 1] = a1;
      if (t0 + 2 < T_TOTAL) s[t0 + 2] = a2;
      if (t0 + 3 < T_TOTAL) s[t0 + 3] = a3;
    }
  }

  if (lane == 0) red[wave] = wmax;
  __syncthreads();
  if (threadIdx.x == 0) {
    float bm = fmaxf(fmaxf(red[0], red[1]), fmaxf(red[2], red[3]));
    ws[MAXP_OFF + blockIdx.x] = bm;
  }
}

// ---------------------------------------------------------------------------
// Kernel 3: M = max over per-block max partials -> STAT[0]. One wave.
// ---------------------------------------------------------------------------
__global__ __launch_bounds__(64) void maxred_kernel(float* __restrict__ ws,
                                                    int n_parts) {
  const int lane = threadIdx.x;
  float m = -1e30f;
  for (int i = lane; i < n_parts; i += 64) m = fmaxf(m, ws[MAXP_OFF + i]);
#pragma unroll
  for (int off = 32; off; off >>= 1) m = fmaxf(m, __shfl_xor(m, off));
  if (lane == 0) ws[STAT_OFF] = m;
}

// ---------------------------------------------------------------------------
// Kernel 4: p[t] = exp(s[t]-M) computed on the fly into LDS; y==0 blocks also
// emit per-chunk denominator partials; then partial[chunk][d] += p[t]*V[t][d].
// Grid (n_chunks, 4): block owns a 1024-float column quarter.
// ---------------------------------------------------------------------------
__global__ __launch_bounds__(256) void pv_kernel(
    const float* __restrict__ Vc, float* __restrict__ ws, int chunk_sz) {
  const float* s    = ws + S_OFF;
  const float* vvec = ws + V_OFF;
  float* partial    = ws + PART_OFF;

  const int chunk = blockIdx.x;
  const int t0 = chunk * chunk_sz;
  const int tend = min(t0 + chunk_sz, T_TOTAL);
  const int n_local = tend - t0;
  const float M = ws[STAT_OFF];

  __shared__ float pl[4096];
  __shared__ float red[4];
  for (int i = threadIdx.x; i < chunk_sz; i += 256) {
    const int t = t0 + i;
    pl[i] = (t < T_TOTAL) ? expf(s[t] - M) : 0.f;
  }
  __syncthreads();

  if (blockIdx.y == 0) {  // denominator partial for this chunk
    const int lane = threadIdx.x & 63, wave = threadIdx.x >> 6;
    float sum = 0.f;
    for (int i = threadIdx.x; i < n_local; i += 256) sum += pl[i];
#pragma unroll
    for (int off = 32; off; off >>= 1) sum += __shfl_xor(sum, off);
    if (lane == 0) red[wave] = sum;
    __syncthreads();
    if (threadIdx.x == 0)
      ws[DENP_OFF + chunk] = red[0] + red[1] + red[2] + red[3];
  }

  const int col = blockIdx.y * 1024 + threadIdx.x * 4;
  float4 acc = {0.f, 0.f, 0.f, 0.f};
#pragma unroll 4
  for (int t = t0; t < tend; ++t) {
    const float* row = (t < T_CACHE) ? (Vc + (size_t)t * DIM) : vvec;
    float4 val = *(const float4*)(row + col);
    const float w = pl[t - t0];
    acc.x += w * val.x; acc.y += w * val.y;
    acc.z += w * val.z; acc.w += w * val.w;
  }
  *(float4*)(partial + (size_t)chunk * DIM + col) = acc;
}

// ---------------------------------------------------------------------------
// Kernel 5: out[d] = sum_c partial[c][d] / sum_c denpart[c].
// ---------------------------------------------------------------------------
__global__ __launch_bounds__(256) void reduce_kernel(
    const float* __restrict__ ws, float* __restrict__ out, int n_chunks) {
  const float* partial = ws + PART_OFF;
  __shared__ float red[4];
  const int lane = threadIdx.x & 63, wave = threadIdx.x >> 6;

  // Redundant per-block denominator reduce (n_chunks <= 512 values).
  float dsum = 0.f;
  for (int c = threadIdx.x; c < n_chunks; c += 256) dsum += ws[DENP_OFF + c];
#pragma unroll
  for (int off = 32; off; off >>= 1) dsum += __shfl_xor(dsum, off);
  if (lane == 0) red[wave] = dsum;
  __syncthreads();
  const float denom = red[0] + red[1] + red[2] + red[3];

  const int d = blockIdx.x * 256 + threadIdx.x;
  float acc = 0.f;
  for (int c = 0; c < n_chunks; ++c) acc += partial[(size_t)c * DIM + d];
  out[d] = acc / denom;
}

// ---------------------------------------------------------------------------
extern "C" void kernel_launch(void* const* d_in, const int* in_sizes, int n_in,
                              void* d_out, int out_size, void* d_ws,
                              size_t ws_size, hipStream_t stream) {
  const float* x  = (const float*)d_in[0];
  const float* Kc = (const float*)d_in[1];
  const float* Vc = (const float*)d_in[2];
  const float* Wq = (const float*)d_in[3];
  const float* bq = (const float*)d_in[4];
  const float* Wk = (const float*)d_in[5];
  const float* bk = (const float*)d_in[6];
  const float* Wv = (const float*)d_in[7];
  const float* bv = (const float*)d_in[8];
  float* ws  = (float*)d_ws;
  float* out = (float*)d_out;

  // Pick PV chunk size so the partial buffer fits in ws (deterministic:
  // ws_size is constant across calls). chunk_sz may grow up to 4096 (the LDS
  // pl[] capacity) if ws is small; default 128 -> 257 chunks (~4.2 MB).
  const size_t avail_f = (ws_size / 4 > (size_t)PART_OFF)
                             ? ws_size / 4 - PART_OFF : 0;
  const int max_chunks = (int)(avail_f / DIM);
  int chunk_sz = 128;
  while (chunk_sz < 4096 && (T_TOTAL + chunk_sz - 1) / chunk_sz > max_chunks)
    chunk_sz <<= 1;
  const int n_chunks = (T_TOTAL + chunk_sz - 1) / chunk_sz;

  const int n_score_blocks = (T_TOTAL + 31) / 32;  // 4 waves * 8 rows = 32/blk

  qkv_gemv<<<3072, 256, 0, stream>>>(x, Wq, bq, Wk, bk, Wv, bv, ws);
  scores_kernel<<<n_score_blocks, 256, 0, stream>>>(Kc, ws);
  maxred_kernel<<<1, 64, 0, stream>>>(ws, n_score_blocks);
  pv_kernel<<<dim3(n_chunks, 4), 256, 0, stream>>>(Vc, ws, chunk_sz);
  reduce_kernel<<<16, 256, 0, stream>>>(ws, out, n_chunks);
}